// Round 20
// baseline (194.467 us; speedup 1.0000x reference)
//
#include <hip/hip_runtime.h>
#include <math.h>

typedef _Float16 h16;
typedef _Float16 h16x4 __attribute__((ext_vector_type(4)));
typedef _Float16 h16x8 __attribute__((ext_vector_type(8)));
typedef float    f32x4 __attribute__((ext_vector_type(4)));

#define Bsz 2
#define Tsz 2048
#define Dsz 1024
#define Hn  16
#define DH  64
#define NC  32         // scan chunks
#define NCSH 5
#define CL  (Tsz/NC)   // 64 steps per chunk
#define TS  16         // steps per LDS tile (scan)
#define NTL (CL/TS)    // 4 tiles per chunk
#define LP  68         // padded LDS row (floats) for scan tiles

// ---------------------------------------------------------------------------
// prep: fused weight-convert (blocks 0..3583) + x_shift build (3584..5631).
__global__ void prep(const float* __restrict__ s0, const float* __restrict__ s1,
                     const float* __restrict__ s2, const float* __restrict__ s3,
                     const float* __restrict__ s4, const float* __restrict__ s5,
                     const float* __restrict__ s6, h16* __restrict__ dst,
                     const float* __restrict__ x, h16* __restrict__ xs) {
    int blk = blockIdx.x;
    if (blk < 7 * 512) {
        int seg = blk >> 9;
        int li  = ((blk & 511) << 8) + threadIdx.x;
        const float* sp;
        switch (seg) {
            case 0: sp = s0; break; case 1: sp = s1; break; case 2: sp = s2; break;
            case 3: sp = s3; break; case 4: sp = s4; break; case 5: sp = s5; break;
            default: sp = s6; break;
        }
        size_t e = (size_t)li * 8;
        f32x4 a = *(const f32x4*)(sp + e);
        f32x4 b = *(const f32x4*)(sp + e + 4);
        h16x8 o;
        #pragma unroll
        for (int j = 0; j < 4; ++j) { o[j] = (h16)a[j]; o[j + 4] = (h16)b[j]; }
        *(h16x8*)(dst + (size_t)seg * 1048576 + e) = o;
    } else {
        int li = ((blk - 7 * 512) << 8) + threadIdx.x;
        size_t e = (size_t)li * 8;
        int tok = (int)(e >> 10);
        int t   = tok & (Tsz - 1);
        h16x8 o;
        if (t > 0) {
            f32x4 a = *(const f32x4*)(x + e - Dsz);
            f32x4 b = *(const f32x4*)(x + e - Dsz + 4);
            #pragma unroll
            for (int j = 0; j < 4; ++j) { o[j] = (h16)a[j]; o[j + 4] = (h16)b[j]; }
        } else {
            #pragma unroll
            for (int j = 0; j < 8; ++j) o[j] = (h16)0.f;
        }
        *(h16x8*)(xs + e) = o;
    }
}

// ---------------------------------------------------------------------------
// GEMM core (r17 known-good): depth-4 counted-vmcnt pipeline, 5 LDS buffer
// pairs (80KB, 2 blocks/CU): [vmcnt(12) -> s_barrier -> stage(t+4) ->
// compute(t%5)]. T4/T5, XCD swizzle, chunk swizzle (conflicts 0).
#define BK 32

__device__ __forceinline__ void gld16(const void* g, void* l) {
    __builtin_amdgcn_global_load_lds(
        (const __attribute__((address_space(1))) void*)g,
        (__attribute__((address_space(3))) void*)l, 16, 0, 0);
}

struct GemmCtx {
    f32x4 acc[4][4];
    int bm, bn, lane, wave, wm, wn;
};

__device__ __forceinline__ void gemm_kloop(GemmCtx& cx, const h16* __restrict__ A,
                                           const h16* __restrict__ W) {
    __shared__ h16 As[5][4096];
    __shared__ h16 Bs[5][4096];
    const int tid  = threadIdx.x;
    const int lane = tid & 63;
    const int wave = tid >> 6;
    cx.lane = lane; cx.wave = wave;
    cx.wm = (wave >> 1) * 64;
    cx.wn = (wave & 1) * 64;
    const int lin = blockIdx.y * 8 + blockIdx.x;      // 0..255
    const int g8  = lin & 7, sq = lin >> 3;
    cx.bm = (g8 * 4 + (sq >> 3)) * 128;
    cx.bn = (sq & 7) * 128;
    const int K = 1024;

    #pragma unroll
    for (int a = 0; a < 4; ++a)
        #pragma unroll
        for (int b = 0; b < 4; ++b) cx.acc[a][b] = (f32x4)(0.f);

    const int srow = (wave << 4) + (lane >> 2);
    const int scol = (((lane & 3) ^ ((lane >> 3) & 3)) << 3);
    const h16* gA0 = A + (size_t)(cx.bm + srow) * K + scol;
    const h16* gA1 = gA0 + (size_t)64 * K;
    const h16* gB0 = W + (size_t)(cx.bn + srow) * K + scol;
    const h16* gB1 = gB0 + (size_t)64 * K;

    const int pcq = (lane >> 4) ^ ((lane >> 1) & 3);
    const int fro = (lane & 15) * BK + pcq * 8;

    auto stage = [&](int b, int k0) {
        gld16(gA0 + k0, &As[b][wave * 512]);
        gld16(gA1 + k0, &As[b][2048 + wave * 512]);
        gld16(gB0 + k0, &Bs[b][wave * 512]);
        gld16(gB1 + k0, &Bs[b][2048 + wave * 512]);
    };
    auto compute = [&](int b) {
        const h16* as = As[b]; const h16* bs = Bs[b];
        h16x8 af[4], bfr[4];
        #pragma unroll
        for (int mi = 0; mi < 4; ++mi)
            af[mi] = *(const h16x8*)(as + (cx.wm + mi * 16) * BK + fro);
        #pragma unroll
        for (int ni = 0; ni < 4; ++ni)
            bfr[ni] = *(const h16x8*)(bs + (cx.wn + ni * 16) * BK + fro);
        __builtin_amdgcn_s_setprio(1);
        #pragma unroll
        for (int mi = 0; mi < 4; ++mi)
            #pragma unroll
            for (int ni = 0; ni < 4; ++ni)
                cx.acc[mi][ni] = __builtin_amdgcn_mfma_f32_16x16x32_f16(
                    af[mi], bfr[ni], cx.acc[mi][ni], 0, 0, 0);
        __builtin_amdgcn_s_setprio(0);
    };

    stage(0, 0);
    stage(1, BK);
    stage(2, 2 * BK);
    stage(3, 3 * BK);
    #pragma unroll
    for (int t = 0; t < 32; ++t) {
        if (t <= 28)      { asm volatile("s_waitcnt vmcnt(12)" ::: "memory"); }
        else if (t == 29) { asm volatile("s_waitcnt vmcnt(8)"  ::: "memory"); }
        else if (t == 30) { asm volatile("s_waitcnt vmcnt(4)"  ::: "memory"); }
        else              { asm volatile("s_waitcnt vmcnt(0)"  ::: "memory"); }
        __builtin_amdgcn_sched_barrier(0);
        __builtin_amdgcn_s_barrier();
        __builtin_amdgcn_sched_barrier(0);
        if (t + 4 < 32) stage((t + 4) % 5, (t + 4) * BK);
        compute(t % 5);
    }
}

// Plain GEMM with scalar epilogue, templated output.
// epi: 0=raw, 2=silu(y), 3=e^-0.5*sigmoid(y)
template <typename OT>
__device__ __forceinline__ void gemm_body(const h16* __restrict__ A,
                                          const h16* __restrict__ W,
                                          OT* __restrict__ C, int epi) {
    GemmCtx cx;
    gemm_kloop(cx, A, W);
    const int colb = cx.bn + cx.wn + (cx.lane & 15);
    const int rowb = cx.bm + cx.wm + (cx.lane >> 4) * 4;
    #pragma unroll
    for (int mi = 0; mi < 4; ++mi)
        #pragma unroll
        for (int ni = 0; ni < 4; ++ni)
            #pragma unroll
            for (int j = 0; j < 4; ++j) {
                float y = cx.acc[mi][ni][j];
                if (epi == 2)      { y = y / (1.f + __expf(-y)); }
                else if (epi == 3) { y = 0.60653065971263342f / (1.f + __expf(-y)); }
                C[(size_t)(rowb + mi * 16 + j) * 1024 + colb + ni * 16] = (OT)y;
            }
}

__global__ __launch_bounds__(256) void gemm_bt_f(const h16* __restrict__ A,
                                                 const h16* __restrict__ W,
                                                 float* __restrict__ C, int epi) {
    gemm_body<float>(A, W, C, epi);
}

// dd GEMM with fused 5-way lerp epilogue (fast-exp tanh/sigmoid).
// r20: x_shift re-read replaced by A (== xs, h16) — A[e] is exactly the
// shifted row this GEMM consumed; drops 8MB f32 reads + the t>0 branch.
__global__ __launch_bounds__(256) void gemm_ddlerp(const h16* __restrict__ A,
                                                   const h16* __restrict__ W,
                                                   const float* __restrict__ x,
                                                   const float* __restrict__ mr,
                                                   const float* __restrict__ mk,
                                                   const float* __restrict__ mv,
                                                   const float* __restrict__ mg,
                                                   const float* __restrict__ mw,
                                                   h16* __restrict__ ar, h16* __restrict__ ak,
                                                   h16* __restrict__ av, h16* __restrict__ ag,
                                                   h16* __restrict__ aw) {
    GemmCtx cx;
    gemm_kloop(cx, A, W);
    const int colb = cx.bn + cx.wn + (cx.lane & 15);
    const int rowb = cx.bm + cx.wm + (cx.lane >> 4) * 4;
    #pragma unroll
    for (int mi = 0; mi < 4; ++mi)
        #pragma unroll
        for (int j = 0; j < 4; ++j) {
            int m = rowb + mi * 16 + j;
            #pragma unroll
            for (int ni = 0; ni < 4; ++ni) {
                int d = colb + ni * 16;
                size_t e = (size_t)m * 1024 + d;
                float y  = cx.acc[mi][ni][j];
                float th = 1.f - 2.f / (__expf(2.f * y) + 1.f);
                float dv = 1.f / (1.f + __expf(-th));
                float xv  = x[e];
                float xsv = (float)A[e];
                float dxx = xv - xsv;
                float m0 = mr[d], m1 = mk[d], m2 = mv[d], m3 = mg[d], m4 = mw[d];
                ar[e] = (h16)(xsv + dxx * (m0 + dv * (1.f - m0)));
                ak[e] = (h16)(xsv + dxx * (m1 + dv * (1.f - m1)));
                av[e] = (h16)(xsv + dxx * (m2 + dv * (1.f - m2)));
                ag[e] = (h16)(xsv + dxx * (m3 + dv * (1.f - m3)));
                aw[e] = (h16)(xsv + dxx * (m4 + dv * (1.f - m4)));
            }
        }
}

__global__ __launch_bounds__(256) void gemm5(const h16* __restrict__ A0, const h16* __restrict__ A1,
                                             const h16* __restrict__ A2, const h16* __restrict__ A3,
                                             const h16* __restrict__ A4, const h16* __restrict__ Wb,
                                             h16* __restrict__ C0, h16* __restrict__ C1,
                                             h16* __restrict__ C2, h16* __restrict__ C3,
                                             h16* __restrict__ C4) {
    int z = blockIdx.z;
    const h16* A; h16* C; int epi;
    switch (z) {
        case 0: A = A0; C = C0; epi = 0; break;
        case 1: A = A1; C = C1; epi = 0; break;
        case 2: A = A2; C = C2; epi = 0; break;
        case 3: A = A3; C = C3; epi = 2; break;
        default: A = A4; C = C4; epi = 3; break;
    }
    gemm_body<h16>(A, Wb + (size_t)(z + 1) * 1048576, C, epi);
}

// ---------------------------------------------------------------------------
// WKV scan, NC=32; f16 globals + f16 state.
__device__ __forceinline__ void cvt16(const h16x8 u0, const h16x8 u1,
                                      f32x4& t0, f32x4& t1, f32x4& t2, f32x4& t3) {
    #pragma unroll
    for (int j = 0; j < 4; ++j) {
        t0[j] = (float)u0[j];     t1[j] = (float)u0[j + 4];
        t2[j] = (float)u1[j];     t3[j] = (float)u1[j + 4];
    }
}

__global__ __launch_bounds__(256) void wkv_pass1(const h16* __restrict__ kk,
                                                 const h16* __restrict__ vv,
                                                 const h16* __restrict__ ew,
                                                 h16* __restrict__ Abuf,
                                                 float* __restrict__ Pbuf) {
    __shared__ float lds[2][3][TS][LP];
    int blk = blockIdx.x;
    int bh = blk >> NCSH, c = blk & (NC - 1);
    int b = bh >> 4, h = bh & 15;
    int tid = threadIdx.x;
    int i = tid >> 2, q = tid & 3, j0 = q * 16;
    int w = tid >> 6, idx = tid & 63;
    int ss = idx >> 2, qq = idx & 3;
    const h16* sarr = (w == 0) ? ew : (w == 1) ? kk : vv;

    float st[16];
    #pragma unroll
    for (int jj = 0; jj < 16; ++jj) st[jj] = 0.f;
    float pp = 1.f;

    size_t cbase = ((size_t)b * Tsz + (size_t)c * CL) * Dsz + h * DH;

    if (w < 3) {
        const h16x8* g = (const h16x8*)(sarr + cbase + (size_t)ss * Dsz + qq * 16);
        h16x8 u0 = g[0], u1 = g[1];
        f32x4 t0, t1, t2, t3;
        cvt16(u0, u1, t0, t1, t2, t3);
        f32x4* d = (f32x4*)&lds[0][w][ss][qq * 16];
        d[0] = t0; d[1] = t1; d[2] = t2; d[3] = t3;
    }
    __syncthreads();

    for (int tl = 0; tl < NTL; ++tl) {
        int cur = tl & 1;
        h16x8 u0, u1;
        bool pf = (tl + 1 < NTL) && (w < 3);
        if (pf) {
            const h16x8* g = (const h16x8*)(sarr + cbase + (size_t)(tl + 1) * TS * Dsz
                                            + (size_t)ss * Dsz + qq * 16);
            u0 = g[0]; u1 = g[1];
        }
        #pragma unroll 4
        for (int s = 0; s < TS; ++s) {
            float ewi = lds[cur][0][s][i];
            float ki  = lds[cur][1][s][i];
            const float* vrow = &lds[cur][2][s][0];
            f32x4 v0 = *(const f32x4*)(vrow + j0);
            f32x4 v1 = *(const f32x4*)(vrow + j0 + 4);
            f32x4 v2 = *(const f32x4*)(vrow + j0 + 8);
            f32x4 v3 = *(const f32x4*)(vrow + j0 + 12);
            #pragma unroll
            for (int jj = 0; jj < 4; ++jj) {
                st[jj]      = fmaf(st[jj],      ewi, ki * v0[jj]);
                st[jj + 4]  = fmaf(st[jj + 4],  ewi, ki * v1[jj]);
                st[jj + 8]  = fmaf(st[jj + 8],  ewi, ki * v2[jj]);
                st[jj + 12] = fmaf(st[jj + 12], ewi, ki * v3[jj]);
            }
            pp *= ewi;
        }
        if (pf) {
            f32x4 t0, t1, t2, t3;
            cvt16(u0, u1, t0, t1, t2, t3);
            f32x4* d = (f32x4*)&lds[cur ^ 1][w][ss][qq * 16];
            d[0] = t0; d[1] = t1; d[2] = t2; d[3] = t3;
        }
        __syncthreads();
    }

    size_t ob = (size_t)blk * 4096 + (size_t)i * 64 + j0;
    h16x8 s0, s1;
    #pragma unroll
    for (int jj = 0; jj < 8; ++jj) { s0[jj] = (h16)st[jj]; s1[jj] = (h16)st[jj + 8]; }
    *(h16x8*)(Abuf + ob)     = s0;
    *(h16x8*)(Abuf + ob + 8) = s1;
    if (q == 0) Pbuf[blk * 64 + i] = pp;
}

// IN-PLACE combine, j-split x4 (grid 128 blocks), depth-2 prefetch, f16 state.
__global__ __launch_bounds__(256) void wkv_combine(h16* __restrict__ AS,
                                                   const float* __restrict__ Pbuf) {
    int bh = blockIdx.x >> 2, jq = blockIdx.x & 3;
    int tid = threadIdx.x;
    int i = tid >> 2, sc = tid & 3;
    int off = i * 64 + jq * 16 + sc * 4;
    float s[4] = {0.f, 0.f, 0.f, 0.f};
    size_t base = (size_t)(bh * NC) * 4096 + off;
    h16x4 a0 = *(const h16x4*)(AS + base);
    float p0 = Pbuf[bh * NC * 64 + i];
    h16x4 a1 = *(const h16x4*)(AS + base + 4096);
    float p1 = Pbuf[(bh * NC + 1) * 64 + i];
    for (int c = 0; c < NC; ++c) {
        h16x4 a2{}; float p2 = 0.f;
        if (c + 2 < NC) {
            a2 = *(const h16x4*)(AS + base + 2 * 4096);
            p2 = Pbuf[(bh * NC + c + 2) * 64 + i];
        }
        h16x4 so;
        #pragma unroll
        for (int j = 0; j < 4; ++j) so[j] = (h16)s[j];
        *(h16x4*)(AS + base) = so;
        #pragma unroll
        for (int j = 0; j < 4; ++j) s[j] = fmaf(s[j], p0, (float)a0[j]);
        a0 = a1; p0 = p1; a1 = a2; p1 = p2;
        base += 4096;
    }
}

// pass2 + fused GroupNorm/gate (r20): per timestep, this block's 64 outputs
// are exactly one GN group (head h, 64 channels). po collected in LDS;
// per tile each wave normalizes 4 timesteps (64-lane shuffle reduce),
// applies gnw/gnb + silu-gate, writes `gated` coalesced. Eliminates the
// gn_gate dispatch and the obuf round-trip.
__global__ __launch_bounds__(256) void wkv_pass2(const h16* __restrict__ rr,
                                                 const h16* __restrict__ kk,
                                                 const h16* __restrict__ vv,
                                                 const h16* __restrict__ ew,
                                                 const h16* __restrict__ Sbuf,
                                                 const h16* __restrict__ gb,
                                                 const float* __restrict__ gnw,
                                                 const float* __restrict__ gnb,
                                                 h16* __restrict__ gated) {
    __shared__ float lds[2][4][TS][LP];
    __shared__ float po_buf[TS][65];
    int blk = blockIdx.x;
    int bh = blk >> NCSH, c = blk & (NC - 1);
    int b = bh >> 4, h = bh & 15;
    int tid = threadIdx.x;
    int i = tid >> 2, q = tid & 3, j0 = q * 16;
    int w = tid >> 6, idx = tid & 63;
    int ss = idx >> 2, qq = idx & 3;
    const h16* sarr = (w == 0) ? ew : (w == 1) ? kk : (w == 2) ? vv : rr;

    const int lane = tid & 63;
    const float gw = gnw[h * 64 + lane];
    const float gbv = gnb[h * 64 + lane];

    float st[16];
    {
        size_t ob = (size_t)blk * 4096 + (size_t)i * 64 + j0;
        h16x8 s0 = *(const h16x8*)(Sbuf + ob);
        h16x8 s1 = *(const h16x8*)(Sbuf + ob + 8);
        #pragma unroll
        for (int jj = 0; jj < 8; ++jj) { st[jj] = (float)s0[jj]; st[jj + 8] = (float)s1[jj]; }
    }

    size_t cbase = ((size_t)b * Tsz + (size_t)c * CL) * Dsz + h * DH;

    {
        const h16x8* g = (const h16x8*)(sarr + cbase + (size_t)ss * Dsz + qq * 16);
        h16x8 u0 = g[0], u1 = g[1];
        f32x4 t0, t1, t2, t3;
        cvt16(u0, u1, t0, t1, t2, t3);
        f32x4* d = (f32x4*)&lds[0][w][ss][qq * 16];
        d[0] = t0; d[1] = t1; d[2] = t2; d[3] = t3;
    }
    __syncthreads();

    for (int tl = 0; tl < NTL; ++tl) {
        int cur = tl & 1;
        h16x8 u0, u1;
        bool pf = (tl + 1 < NTL);
        if (pf) {
            const h16x8* g = (const h16x8*)(sarr + cbase + (size_t)(tl + 1) * TS * Dsz
                                            + (size_t)ss * Dsz + qq * 16);
            u0 = g[0]; u1 = g[1];
        }
        size_t gt = cbase + (size_t)tl * TS * Dsz;
        #pragma unroll 4
        for (int s = 0; s < TS; ++s) {
            float ewi = lds[cur][0][s][i];
            float ki  = lds[cur][1][s][i];
            const float* vrow = &lds[cur][2][s][0];
            const float* rrow = &lds[cur][3][s][0];
            f32x4 v0 = *(const f32x4*)(vrow + j0);
            f32x4 v1 = *(const f32x4*)(vrow + j0 + 4);
            f32x4 v2 = *(const f32x4*)(vrow + j0 + 8);
            f32x4 v3 = *(const f32x4*)(vrow + j0 + 12);
            f32x4 r0 = *(const f32x4*)(rrow + j0);
            f32x4 r1 = *(const f32x4*)(rrow + j0 + 4);
            f32x4 r2 = *(const f32x4*)(rrow + j0 + 8);
            f32x4 r3 = *(const f32x4*)(rrow + j0 + 12);
            float po = 0.f;
            #pragma unroll
            for (int jj = 0; jj < 4; ++jj) {
                st[jj]      = fmaf(st[jj],      ewi, ki * v0[jj]);
                st[jj + 4]  = fmaf(st[jj + 4],  ewi, ki * v1[jj]);
                st[jj + 8]  = fmaf(st[jj + 8],  ewi, ki * v2[jj]);
                st[jj + 12] = fmaf(st[jj + 12], ewi, ki * v3[jj]);
                po = fmaf(st[jj],      r0[jj], po);
                po = fmaf(st[jj + 4],  r1[jj], po);
                po = fmaf(st[jj + 8],  r2[jj], po);
                po = fmaf(st[jj + 12], r3[jj], po);
            }
            po += __shfl_xor(po, 1, 64);
            po += __shfl_xor(po, 2, 64);
            if (q == 0) po_buf[s][i] = po;
        }
        __syncthreads();          // po_buf complete for this tile
        // fused GroupNorm + gate: wave w handles timesteps w*4 .. w*4+3
        #pragma unroll
        for (int k2 = 0; k2 < 4; ++k2) {
            int s2 = w * 4 + k2;
            float val = po_buf[s2][lane];
            float sm = val, sm2 = val * val;
            #pragma unroll
            for (int m = 1; m < 64; m <<= 1) {
                sm  += __shfl_xor(sm, m, 64);
                sm2 += __shfl_xor(sm2, m, 64);
            }
            float mean = sm * (1.f / 64.f);
            float var  = sm2 * (1.f / 64.f) - mean * mean;
            float y = (val - mean) * rsqrtf(var + 0.00064f);
            y = y * gw + gbv;
            size_t ge = gt + (size_t)s2 * Dsz + lane;
            y *= (float)gb[ge];
            gated[ge] = (h16)y;
        }
        if (pf) {
            f32x4 t0, t1, t2, t3;
            cvt16(u0, u1, t0, t1, t2, t3);
            f32x4* d = (f32x4*)&lds[cur ^ 1][w][ss][qq * 16];
            d[0] = t0; d[1] = t1; d[2] = t2; d[3] = t3;
        }
        __syncthreads();
    }
}

// ---------------------------------------------------------------------------
extern "C" void kernel_launch(void* const* d_in, const int* in_sizes, int n_in,
                              void* d_out, int out_size, void* d_ws, size_t ws_size,
                              hipStream_t stream) {
    const float* x      = (const float*)d_in[0];
    const float* ddw    = (const float*)d_in[1];
    const float* mix_r  = (const float*)d_in[2];
    const float* mix_k  = (const float*)d_in[3];
    const float* mix_v  = (const float*)d_in[4];
    const float* mix_g  = (const float*)d_in[5];
    const float* mix_w  = (const float*)d_in[6];
    const float* r_w    = (const float*)d_in[7];
    const float* k_w    = (const float*)d_in[8];
    const float* v_w    = (const float*)d_in[9];
    const float* g_w    = (const float*)d_in[10];
    const float* w_w    = (const float*)d_in[11];
    const float* out_w  = (const float*)d_in[12];
    const float* gnw    = (const float*)d_in[13];
    const float* gnb    = (const float*)d_in[14];

    char* wsb = (char*)d_ws;
    const size_t MB = 1 << 20;
    h16*   wb    = (h16*)  (wsb);             // 14 MB (7 x 2MB f16 weights)
    h16*   xs    = (h16*)  (wsb + 14 * MB);   //  8 MB
    h16*   a_r   = (h16*)  (wsb + 22 * MB);   //  8 MB each
    h16*   a_k   = (h16*)  (wsb + 30 * MB);
    h16*   a_v   = (h16*)  (wsb + 38 * MB);
    h16*   a_g   = (h16*)  (wsb + 46 * MB);
    h16*   a_w   = (h16*)  (wsb + 54 * MB);
    h16*   rb    = (h16*)  (wsb + 62 * MB);   //  8 MB each
    h16*   kb    = (h16*)  (wsb + 70 * MB);
    h16*   vb    = (h16*)  (wsb + 78 * MB);
    h16*   gb    = (h16*)  (wsb + 86 * MB);
    h16*   ewb   = (h16*)  (wsb + 94 * MB);
    h16*   gated = (h16*)  (wsb + 102 * MB);  //  8 MB (end: 110 MB)
    // overlays on the a_* region (dead once the 5 projections are done):
    h16*   Abuf  = (h16*)  (wsb + 22 * MB);   //  8.4 MB (f16, in-place A->S)
    float* Pbuf  = (float*)(wsb + 31 * MB);   //  0.25 MB

    // 1. weights -> f16 + x_shift -> f16 (fused)
    prep<<<7 * 512 + 2048, 256, 0, stream>>>(ddw, r_w, k_w, v_w, g_w, w_w, out_w,
                                             wb, x, xs);
    // 2. dd GEMM + fused 5-way lerp -> f16 activations
    dim3 gg(8, 32);
    gemm_ddlerp<<<gg, 256, 0, stream>>>(xs, wb, x, mix_r, mix_k, mix_v, mix_g, mix_w,
                                        a_r, a_k, a_v, a_g, a_w);
    // 3. batched projections (r,k,v,g-silu,w-exp) -> f16
    dim3 gg5(8, 32, 5);
    gemm5<<<gg5, 256, 0, stream>>>(a_r, a_k, a_v, a_g, a_w, wb, rb, kb, vb, gb, ewb);
    // 4-6. chunked WKV scan; pass2 fuses GroupNorm + gate
    wkv_pass1<<<32 * NC, 256, 0, stream>>>(kb, vb, ewb, Abuf, Pbuf);
    wkv_combine<<<32 * 4, 256, 0, stream>>>(Abuf, Pbuf);
    wkv_pass2<<<32 * NC, 256, 0, stream>>>(rb, kb, vb, ewb, Abuf, gb, gnw, gnb, gated);
    // 7. output projection (f32 out)
    gemm_bt_f<<<gg, 256, 0, stream>>>(gated, wb + 6 * 1048576, (float*)d_out, 0);
    (void)in_sizes; (void)n_in; (void)out_size; (void)ws_size;
}

// Round 21
// 192.084 us; speedup vs baseline: 1.0124x; 1.0124x over previous
//
#include <hip/hip_runtime.h>
#include <math.h>

typedef _Float16 h16;
typedef _Float16 h16x4 __attribute__((ext_vector_type(4)));
typedef _Float16 h16x8 __attribute__((ext_vector_type(8)));
typedef float    f32x4 __attribute__((ext_vector_type(4)));

#define Bsz 2
#define Tsz 2048
#define Dsz 1024
#define Hn  16
#define DH  64
#define NC  32         // scan chunks
#define NCSH 5
#define CL  (Tsz/NC)   // 64 steps per chunk
#define TS  16         // steps per LDS tile (scan)
#define NTL (CL/TS)    // 4 tiles per chunk
#define LP  68         // padded LDS row (floats) for scan tiles

// ---------------------------------------------------------------------------
// prep: fused weight-convert (blocks 0..3583) + x_shift build (3584..5631).
__global__ void prep(const float* __restrict__ s0, const float* __restrict__ s1,
                     const float* __restrict__ s2, const float* __restrict__ s3,
                     const float* __restrict__ s4, const float* __restrict__ s5,
                     const float* __restrict__ s6, h16* __restrict__ dst,
                     const float* __restrict__ x, h16* __restrict__ xs) {
    int blk = blockIdx.x;
    if (blk < 7 * 512) {
        int seg = blk >> 9;
        int li  = ((blk & 511) << 8) + threadIdx.x;
        const float* sp;
        switch (seg) {
            case 0: sp = s0; break; case 1: sp = s1; break; case 2: sp = s2; break;
            case 3: sp = s3; break; case 4: sp = s4; break; case 5: sp = s5; break;
            default: sp = s6; break;
        }
        size_t e = (size_t)li * 8;
        f32x4 a = *(const f32x4*)(sp + e);
        f32x4 b = *(const f32x4*)(sp + e + 4);
        h16x8 o;
        #pragma unroll
        for (int j = 0; j < 4; ++j) { o[j] = (h16)a[j]; o[j + 4] = (h16)b[j]; }
        *(h16x8*)(dst + (size_t)seg * 1048576 + e) = o;
    } else {
        int li = ((blk - 7 * 512) << 8) + threadIdx.x;
        size_t e = (size_t)li * 8;
        int tok = (int)(e >> 10);
        int t   = tok & (Tsz - 1);
        h16x8 o;
        if (t > 0) {
            f32x4 a = *(const f32x4*)(x + e - Dsz);
            f32x4 b = *(const f32x4*)(x + e - Dsz + 4);
            #pragma unroll
            for (int j = 0; j < 4; ++j) { o[j] = (h16)a[j]; o[j + 4] = (h16)b[j]; }
        } else {
            #pragma unroll
            for (int j = 0; j < 8; ++j) o[j] = (h16)0.f;
        }
        *(h16x8*)(xs + e) = o;
    }
}

// ---------------------------------------------------------------------------
#define BK 32

__device__ __forceinline__ void gld16(const void* g, void* l) {
    __builtin_amdgcn_global_load_lds(
        (const __attribute__((address_space(1))) void*)g,
        (__attribute__((address_space(3))) void*)l, 16, 0, 0);
}

// ================== 128x128 kloop (r17, gemm5 only; 1280 blocks) ============
struct GemmCtx {
    f32x4 acc[4][4];
    int bm, bn, lane, wave, wm, wn;
};

__device__ __forceinline__ void gemm_kloop(GemmCtx& cx, const h16* __restrict__ A,
                                           const h16* __restrict__ W) {
    __shared__ h16 As[5][4096];
    __shared__ h16 Bs[5][4096];
    const int tid  = threadIdx.x;
    const int lane = tid & 63;
    const int wave = tid >> 6;
    cx.lane = lane; cx.wave = wave;
    cx.wm = (wave >> 1) * 64;
    cx.wn = (wave & 1) * 64;
    const int lin = blockIdx.y * 8 + blockIdx.x;      // 0..255
    const int g8  = lin & 7, sq = lin >> 3;
    cx.bm = (g8 * 4 + (sq >> 3)) * 128;
    cx.bn = (sq & 7) * 128;
    const int K = 1024;

    #pragma unroll
    for (int a = 0; a < 4; ++a)
        #pragma unroll
        for (int b = 0; b < 4; ++b) cx.acc[a][b] = (f32x4)(0.f);

    const int srow = (wave << 4) + (lane >> 2);
    const int scol = (((lane & 3) ^ ((lane >> 3) & 3)) << 3);
    const h16* gA0 = A + (size_t)(cx.bm + srow) * K + scol;
    const h16* gA1 = gA0 + (size_t)64 * K;
    const h16* gB0 = W + (size_t)(cx.bn + srow) * K + scol;
    const h16* gB1 = gB0 + (size_t)64 * K;

    const int pcq = (lane >> 4) ^ ((lane >> 1) & 3);
    const int fro = (lane & 15) * BK + pcq * 8;

    auto stage = [&](int b, int k0) {
        gld16(gA0 + k0, &As[b][wave * 512]);
        gld16(gA1 + k0, &As[b][2048 + wave * 512]);
        gld16(gB0 + k0, &Bs[b][wave * 512]);
        gld16(gB1 + k0, &Bs[b][2048 + wave * 512]);
    };
    auto compute = [&](int b) {
        const h16* as = As[b]; const h16* bs = Bs[b];
        h16x8 af[4], bfr[4];
        #pragma unroll
        for (int mi = 0; mi < 4; ++mi)
            af[mi] = *(const h16x8*)(as + (cx.wm + mi * 16) * BK + fro);
        #pragma unroll
        for (int ni = 0; ni < 4; ++ni)
            bfr[ni] = *(const h16x8*)(bs + (cx.wn + ni * 16) * BK + fro);
        __builtin_amdgcn_s_setprio(1);
        #pragma unroll
        for (int mi = 0; mi < 4; ++mi)
            #pragma unroll
            for (int ni = 0; ni < 4; ++ni)
                cx.acc[mi][ni] = __builtin_amdgcn_mfma_f32_16x16x32_f16(
                    af[mi], bfr[ni], cx.acc[mi][ni], 0, 0, 0);
        __builtin_amdgcn_s_setprio(0);
    };

    stage(0, 0);
    stage(1, BK);
    stage(2, 2 * BK);
    stage(3, 3 * BK);
    #pragma unroll
    for (int t = 0; t < 32; ++t) {
        if (t <= 28)      { asm volatile("s_waitcnt vmcnt(12)" ::: "memory"); }
        else if (t == 29) { asm volatile("s_waitcnt vmcnt(8)"  ::: "memory"); }
        else if (t == 30) { asm volatile("s_waitcnt vmcnt(4)"  ::: "memory"); }
        else              { asm volatile("s_waitcnt vmcnt(0)"  ::: "memory"); }
        __builtin_amdgcn_sched_barrier(0);
        __builtin_amdgcn_s_barrier();
        __builtin_amdgcn_sched_barrier(0);
        if (t + 4 < 32) stage((t + 4) % 5, (t + 4) * BK);
        compute(t % 5);
    }
}

__global__ __launch_bounds__(256) void gemm5(const h16* __restrict__ A0, const h16* __restrict__ A1,
                                             const h16* __restrict__ A2, const h16* __restrict__ A3,
                                             const h16* __restrict__ A4, const h16* __restrict__ Wb,
                                             h16* __restrict__ C0, h16* __restrict__ C1,
                                             h16* __restrict__ C2, h16* __restrict__ C3,
                                             h16* __restrict__ C4) {
    int z = blockIdx.z;
    const h16* A; h16* C; int epi;
    switch (z) {
        case 0: A = A0; C = C0; epi = 0; break;
        case 1: A = A1; C = C1; epi = 0; break;
        case 2: A = A2; C = C2; epi = 0; break;
        case 3: A = A3; C = C3; epi = 2; break;
        default: A = A4; C = C4; epi = 3; break;
    }
    GemmCtx cx;
    gemm_kloop(cx, A, Wb + (size_t)(z + 1) * 1048576);
    const int colb = cx.bn + cx.wn + (cx.lane & 15);
    const int rowb = cx.bm + cx.wm + (cx.lane >> 4) * 4;
    #pragma unroll
    for (int mi = 0; mi < 4; ++mi)
        #pragma unroll
        for (int ni = 0; ni < 4; ++ni)
            #pragma unroll
            for (int j = 0; j < 4; ++j) {
                float y = cx.acc[mi][ni][j];
                if (epi == 2)      { y = y / (1.f + __expf(-y)); }
                else if (epi == 3) { y = 0.60653065971263342f / (1.f + __expf(-y)); }
                C[(size_t)(rowb + mi * 16 + j) * 1024 + colb + ni * 16] = (h16)y;
            }
}

// ============ 64x128 kloop (r21: single-GEMM dispatches, 512 blocks) ========
// Mechanism: ddlerp/bt_f at 256 blocks = 1 block/CU had zero cross-block
// overlap (~27us each vs gemm5's 14.3us/GEMM at 2/CU). 64x128 tile -> 512
// blocks = exactly 2/CU, zero tail. Depth-4, 5 buffers x 12KB = 60KB.
// Per stage: 3 gld16/thread -> steady vmcnt(9), tail 6/3/0.
// XCD swizzle (8,64): XCD g owns 8 consecutive 64-row A-panels (1MB+2MB L2).
struct GemmCtx64 {
    f32x4 acc[4][2];
    int bm, bn, lane, wave, wn;
};

__device__ __forceinline__ void gemm_kloop64(GemmCtx64& cx, const h16* __restrict__ A,
                                             const h16* __restrict__ W) {
    __shared__ h16 As[5][2048];   // 5 x 4KB (64x32)
    __shared__ h16 Bs[5][4096];   // 5 x 8KB (128x32)
    const int tid  = threadIdx.x;
    const int lane = tid & 63;
    const int wave = tid >> 6;
    cx.lane = lane; cx.wave = wave;
    cx.wn = wave * 32;
    const int lin = blockIdx.y * 8 + blockIdx.x;      // 0..511
    const int g8  = lin & 7, sq = lin >> 3;           // sq 0..63
    cx.bm = (g8 * 8 + (sq >> 3)) * 64;                // 64 row-panels
    cx.bn = (sq & 7) * 128;
    const int K = 1024;

    #pragma unroll
    for (int a = 0; a < 4; ++a)
        #pragma unroll
        for (int b = 0; b < 2; ++b) cx.acc[a][b] = (f32x4)(0.f);

    const int srow = (wave << 4) + (lane >> 2);       // 0..63
    const int scol = (((lane & 3) ^ ((lane >> 3) & 3)) << 3);
    const h16* gA0 = A + (size_t)(cx.bm + srow) * K + scol;
    const h16* gB0 = W + (size_t)(cx.bn + srow) * K + scol;
    const h16* gB1 = gB0 + (size_t)64 * K;

    const int pcq = (lane >> 4) ^ ((lane >> 1) & 3);
    const int fro = (lane & 15) * BK + pcq * 8;

    auto stage = [&](int b, int k0) {
        gld16(gA0 + k0, &As[b][wave * 512]);
        gld16(gB0 + k0, &Bs[b][wave * 512]);
        gld16(gB1 + k0, &Bs[b][2048 + wave * 512]);
    };
    auto compute = [&](int b) {
        const h16* as = As[b]; const h16* bs = Bs[b];
        h16x8 af[4], bfr[2];
        #pragma unroll
        for (int mi = 0; mi < 4; ++mi)
            af[mi] = *(const h16x8*)(as + (mi * 16) * BK + fro);
        #pragma unroll
        for (int ni = 0; ni < 2; ++ni)
            bfr[ni] = *(const h16x8*)(bs + (cx.wn + ni * 16) * BK + fro);
        __builtin_amdgcn_s_setprio(1);
        #pragma unroll
        for (int mi = 0; mi < 4; ++mi)
            #pragma unroll
            for (int ni = 0; ni < 2; ++ni)
                cx.acc[mi][ni] = __builtin_amdgcn_mfma_f32_16x16x32_f16(
                    af[mi], bfr[ni], cx.acc[mi][ni], 0, 0, 0);
        __builtin_amdgcn_s_setprio(0);
    };

    stage(0, 0);
    stage(1, BK);
    stage(2, 2 * BK);
    stage(3, 3 * BK);
    #pragma unroll
    for (int t = 0; t < 32; ++t) {
        if (t <= 28)      { asm volatile("s_waitcnt vmcnt(9)" ::: "memory"); }
        else if (t == 29) { asm volatile("s_waitcnt vmcnt(6)" ::: "memory"); }
        else if (t == 30) { asm volatile("s_waitcnt vmcnt(3)" ::: "memory"); }
        else              { asm volatile("s_waitcnt vmcnt(0)" ::: "memory"); }
        __builtin_amdgcn_sched_barrier(0);
        __builtin_amdgcn_s_barrier();
        __builtin_amdgcn_sched_barrier(0);
        if (t + 4 < 32) stage((t + 4) % 5, (t + 4) * BK);
        compute(t % 5);
    }
}

__global__ __launch_bounds__(256) void gemm_bt_f(const h16* __restrict__ A,
                                                 const h16* __restrict__ W,
                                                 float* __restrict__ C) {
    GemmCtx64 cx;
    gemm_kloop64(cx, A, W);
    const int colb = cx.bn + cx.wn + (cx.lane & 15);
    const int rowb = cx.bm + (cx.lane >> 4) * 4;
    #pragma unroll
    for (int mi = 0; mi < 4; ++mi)
        #pragma unroll
        for (int ni = 0; ni < 2; ++ni)
            #pragma unroll
            for (int j = 0; j < 4; ++j)
                C[(size_t)(rowb + mi * 16 + j) * 1024 + colb + ni * 16] = cx.acc[mi][ni][j];
}

// dd GEMM with fused 5-way lerp epilogue (fast-exp tanh/sigmoid);
// x_shift read from A (== xs, h16).
__global__ __launch_bounds__(256) void gemm_ddlerp(const h16* __restrict__ A,
                                                   const h16* __restrict__ W,
                                                   const float* __restrict__ x,
                                                   const float* __restrict__ mr,
                                                   const float* __restrict__ mk,
                                                   const float* __restrict__ mv,
                                                   const float* __restrict__ mg,
                                                   const float* __restrict__ mw,
                                                   h16* __restrict__ ar, h16* __restrict__ ak,
                                                   h16* __restrict__ av, h16* __restrict__ ag,
                                                   h16* __restrict__ aw) {
    GemmCtx64 cx;
    gemm_kloop64(cx, A, W);
    const int colb = cx.bn + cx.wn + (cx.lane & 15);
    const int rowb = cx.bm + (cx.lane >> 4) * 4;
    #pragma unroll
    for (int mi = 0; mi < 4; ++mi)
        #pragma unroll
        for (int j = 0; j < 4; ++j) {
            int m = rowb + mi * 16 + j;
            #pragma unroll
            for (int ni = 0; ni < 2; ++ni) {
                int d = colb + ni * 16;
                size_t e = (size_t)m * 1024 + d;
                float y  = cx.acc[mi][ni][j];
                float th = 1.f - 2.f / (__expf(2.f * y) + 1.f);
                float dv = 1.f / (1.f + __expf(-th));
                float xv  = x[e];
                float xsv = (float)A[e];
                float dxx = xv - xsv;
                float m0 = mr[d], m1 = mk[d], m2 = mv[d], m3 = mg[d], m4 = mw[d];
                ar[e] = (h16)(xsv + dxx * (m0 + dv * (1.f - m0)));
                ak[e] = (h16)(xsv + dxx * (m1 + dv * (1.f - m1)));
                av[e] = (h16)(xsv + dxx * (m2 + dv * (1.f - m2)));
                ag[e] = (h16)(xsv + dxx * (m3 + dv * (1.f - m3)));
                aw[e] = (h16)(xsv + dxx * (m4 + dv * (1.f - m4)));
            }
        }
}

// ---------------------------------------------------------------------------
// WKV scan, NC=32; f16 globals + f16 state. (r20 known-good)
__device__ __forceinline__ void cvt16(const h16x8 u0, const h16x8 u1,
                                      f32x4& t0, f32x4& t1, f32x4& t2, f32x4& t3) {
    #pragma unroll
    for (int j = 0; j < 4; ++j) {
        t0[j] = (float)u0[j];     t1[j] = (float)u0[j + 4];
        t2[j] = (float)u1[j];     t3[j] = (float)u1[j + 4];
    }
}

__global__ __launch_bounds__(256) void wkv_pass1(const h16* __restrict__ kk,
                                                 const h16* __restrict__ vv,
                                                 const h16* __restrict__ ew,
                                                 h16* __restrict__ Abuf,
                                                 float* __restrict__ Pbuf) {
    __shared__ float lds[2][3][TS][LP];
    int blk = blockIdx.x;
    int bh = blk >> NCSH, c = blk & (NC - 1);
    int b = bh >> 4, h = bh & 15;
    int tid = threadIdx.x;
    int i = tid >> 2, q = tid & 3, j0 = q * 16;
    int w = tid >> 6, idx = tid & 63;
    int ss = idx >> 2, qq = idx & 3;
    const h16* sarr = (w == 0) ? ew : (w == 1) ? kk : vv;

    float st[16];
    #pragma unroll
    for (int jj = 0; jj < 16; ++jj) st[jj] = 0.f;
    float pp = 1.f;

    size_t cbase = ((size_t)b * Tsz + (size_t)c * CL) * Dsz + h * DH;

    if (w < 3) {
        const h16x8* g = (const h16x8*)(sarr + cbase + (size_t)ss * Dsz + qq * 16);
        h16x8 u0 = g[0], u1 = g[1];
        f32x4 t0, t1, t2, t3;
        cvt16(u0, u1, t0, t1, t2, t3);
        f32x4* d = (f32x4*)&lds[0][w][ss][qq * 16];
        d[0] = t0; d[1] = t1; d[2] = t2; d[3] = t3;
    }
    __syncthreads();

    for (int tl = 0; tl < NTL; ++tl) {
        int cur = tl & 1;
        h16x8 u0, u1;
        bool pf = (tl + 1 < NTL) && (w < 3);
        if (pf) {
            const h16x8* g = (const h16x8*)(sarr + cbase + (size_t)(tl + 1) * TS * Dsz
                                            + (size_t)ss * Dsz + qq * 16);
            u0 = g[0]; u1 = g[1];
        }
        #pragma unroll 4
        for (int s = 0; s < TS; ++s) {
            float ewi = lds[cur][0][s][i];
            float ki  = lds[cur][1][s][i];
            const float* vrow = &lds[cur][2][s][0];
            f32x4 v0 = *(const f32x4*)(vrow + j0);
            f32x4 v1 = *(const f32x4*)(vrow + j0 + 4);
            f32x4 v2 = *(const f32x4*)(vrow + j0 + 8);
            f32x4 v3 = *(const f32x4*)(vrow + j0 + 12);
            #pragma unroll
            for (int jj = 0; jj < 4; ++jj) {
                st[jj]      = fmaf(st[jj],      ewi, ki * v0[jj]);
                st[jj + 4]  = fmaf(st[jj + 4],  ewi, ki * v1[jj]);
                st[jj + 8]  = fmaf(st[jj + 8],  ewi, ki * v2[jj]);
                st[jj + 12] = fmaf(st[jj + 12], ewi, ki * v3[jj]);
            }
            pp *= ewi;
        }
        if (pf) {
            f32x4 t0, t1, t2, t3;
            cvt16(u0, u1, t0, t1, t2, t3);
            f32x4* d = (f32x4*)&lds[cur ^ 1][w][ss][qq * 16];
            d[0] = t0; d[1] = t1; d[2] = t2; d[3] = t3;
        }
        __syncthreads();
    }

    size_t ob = (size_t)blk * 4096 + (size_t)i * 64 + j0;
    h16x8 s0, s1;
    #pragma unroll
    for (int jj = 0; jj < 8; ++jj) { s0[jj] = (h16)st[jj]; s1[jj] = (h16)st[jj + 8]; }
    *(h16x8*)(Abuf + ob)     = s0;
    *(h16x8*)(Abuf + ob + 8) = s1;
    if (q == 0) Pbuf[blk * 64 + i] = pp;
}

// IN-PLACE combine, j-split x4 (grid 128 blocks), depth-2 prefetch, f16 state.
__global__ __launch_bounds__(256) void wkv_combine(h16* __restrict__ AS,
                                                   const float* __restrict__ Pbuf) {
    int bh = blockIdx.x >> 2, jq = blockIdx.x & 3;
    int tid = threadIdx.x;
    int i = tid >> 2, sc = tid & 3;
    int off = i * 64 + jq * 16 + sc * 4;
    float s[4] = {0.f, 0.f, 0.f, 0.f};
    size_t base = (size_t)(bh * NC) * 4096 + off;
    h16x4 a0 = *(const h16x4*)(AS + base);
    float p0 = Pbuf[bh * NC * 64 + i];
    h16x4 a1 = *(const h16x4*)(AS + base + 4096);
    float p1 = Pbuf[(bh * NC + 1) * 64 + i];
    for (int c = 0; c < NC; ++c) {
        h16x4 a2{}; float p2 = 0.f;
        if (c + 2 < NC) {
            a2 = *(const h16x4*)(AS + base + 2 * 4096);
            p2 = Pbuf[(bh * NC + c + 2) * 64 + i];
        }
        h16x4 so;
        #pragma unroll
        for (int j = 0; j < 4; ++j) so[j] = (h16)s[j];
        *(h16x4*)(AS + base) = so;
        #pragma unroll
        for (int j = 0; j < 4; ++j) s[j] = fmaf(s[j], p0, (float)a0[j]);
        a0 = a1; p0 = p1; a1 = a2; p1 = p2;
        base += 4096;
    }
}

// pass2 + fused GroupNorm/gate (r20 known-good).
__global__ __launch_bounds__(256) void wkv_pass2(const h16* __restrict__ rr,
                                                 const h16* __restrict__ kk,
                                                 const h16* __restrict__ vv,
                                                 const h16* __restrict__ ew,
                                                 const h16* __restrict__ Sbuf,
                                                 const h16* __restrict__ gb,
                                                 const float* __restrict__ gnw,
                                                 const float* __restrict__ gnb,
                                                 h16* __restrict__ gated) {
    __shared__ float lds[2][4][TS][LP];
    __shared__ float po_buf[TS][65];
    int blk = blockIdx.x;
    int bh = blk >> NCSH, c = blk & (NC - 1);
    int b = bh >> 4, h = bh & 15;
    int tid = threadIdx.x;
    int i = tid >> 2, q = tid & 3, j0 = q * 16;
    int w = tid >> 6, idx = tid & 63;
    int ss = idx >> 2, qq = idx & 3;
    const h16* sarr = (w == 0) ? ew : (w == 1) ? kk : (w == 2) ? vv : rr;

    const int lane = tid & 63;
    const float gw = gnw[h * 64 + lane];
    const float gbv = gnb[h * 64 + lane];

    float st[16];
    {
        size_t ob = (size_t)blk * 4096 + (size_t)i * 64 + j0;
        h16x8 s0 = *(const h16x8*)(Sbuf + ob);
        h16x8 s1 = *(const h16x8*)(Sbuf + ob + 8);
        #pragma unroll
        for (int jj = 0; jj < 8; ++jj) { st[jj] = (float)s0[jj]; st[jj + 8] = (float)s1[jj]; }
    }

    size_t cbase = ((size_t)b * Tsz + (size_t)c * CL) * Dsz + h * DH;

    {
        const h16x8* g = (const h16x8*)(sarr + cbase + (size_t)ss * Dsz + qq * 16);
        h16x8 u0 = g[0], u1 = g[1];
        f32x4 t0, t1, t2, t3;
        cvt16(u0, u1, t0, t1, t2, t3);
        f32x4* d = (f32x4*)&lds[0][w][ss][qq * 16];
        d[0] = t0; d[1] = t1; d[2] = t2; d[3] = t3;
    }
    __syncthreads();

    for (int tl = 0; tl < NTL; ++tl) {
        int cur = tl & 1;
        h16x8 u0, u1;
        bool pf = (tl + 1 < NTL);
        if (pf) {
            const h16x8* g = (const h16x8*)(sarr + cbase + (size_t)(tl + 1) * TS * Dsz
                                            + (size_t)ss * Dsz + qq * 16);
            u0 = g[0]; u1 = g[1];
        }
        size_t gt = cbase + (size_t)tl * TS * Dsz;
        #pragma unroll 4
        for (int s = 0; s < TS; ++s) {
            float ewi = lds[cur][0][s][i];
            float ki  = lds[cur][1][s][i];
            const float* vrow = &lds[cur][2][s][0];
            const float* rrow = &lds[cur][3][s][0];
            f32x4 v0 = *(const f32x4*)(vrow + j0);
            f32x4 v1 = *(const f32x4*)(vrow + j0 + 4);
            f32x4 v2 = *(const f32x4*)(vrow + j0 + 8);
            f32x4 v3 = *(const f32x4*)(vrow + j0 + 12);
            f32x4 r0 = *(const f32x4*)(rrow + j0);
            f32x4 r1 = *(const f32x4*)(rrow + j0 + 4);
            f32x4 r2 = *(const f32x4*)(rrow + j0 + 8);
            f32x4 r3 = *(const f32x4*)(rrow + j0 + 12);
            float po = 0.f;
            #pragma unroll
            for (int jj = 0; jj < 4; ++jj) {
                st[jj]      = fmaf(st[jj],      ewi, ki * v0[jj]);
                st[jj + 4]  = fmaf(st[jj + 4],  ewi, ki * v1[jj]);
                st[jj + 8]  = fmaf(st[jj + 8],  ewi, ki * v2[jj]);
                st[jj + 12] = fmaf(st[jj + 12], ewi, ki * v3[jj]);
                po = fmaf(st[jj],      r0[jj], po);
                po = fmaf(st[jj + 4],  r1[jj], po);
                po = fmaf(st[jj + 8],  r2[jj], po);
                po = fmaf(st[jj + 12], r3[jj], po);
            }
            po += __shfl_xor(po, 1, 64);
            po += __shfl_xor(po, 2, 64);
            if (q == 0) po_buf[s][i] = po;
        }
        __syncthreads();
        #pragma unroll
        for (int k2 = 0; k2 < 4; ++k2) {
            int s2 = w * 4 + k2;
            float val = po_buf[s2][lane];
            float sm = val, sm2 = val * val;
            #pragma unroll
            for (int m = 1; m < 64; m <<= 1) {
                sm  += __shfl_xor(sm, m, 64);
                sm2 += __shfl_xor(sm2, m, 64);
            }
            float mean = sm * (1.f / 64.f);
            float var  = sm2 * (1.f / 64.f) - mean * mean;
            float y = (val - mean) * rsqrtf(var + 0.00064f);
            y = y * gw + gbv;
            size_t ge = gt + (size_t)s2 * Dsz + lane;
            y *= (float)gb[ge];
            gated[ge] = (h16)y;
        }
        if (pf) {
            f32x4 t0, t1, t2, t3;
            cvt16(u0, u1, t0, t1, t2, t3);
            f32x4* d = (f32x4*)&lds[cur ^ 1][w][ss][qq * 16];
            d[0] = t0; d[1] = t1; d[2] = t2; d[3] = t3;
        }
        __syncthreads();
    }
}

// ---------------------------------------------------------------------------
extern "C" void kernel_launch(void* const* d_in, const int* in_sizes, int n_in,
                              void* d_out, int out_size, void* d_ws, size_t ws_size,
                              hipStream_t stream) {
    const float* x      = (const float*)d_in[0];
    const float* ddw    = (const float*)d_in[1];
    const float* mix_r  = (const float*)d_in[2];
    const float* mix_k  = (const float*)d_in[3];
    const float* mix_v  = (const float*)d_in[4];
    const float* mix_g  = (const float*)d_in[5];
    const float* mix_w  = (const float*)d_in[6];
    const float* r_w    = (const float*)d_in[7];
    const float* k_w    = (const float*)d_in[8];
    const float* v_w    = (const float*)d_in[9];
    const float* g_w    = (const float*)d_in[10];
    const float* w_w    = (const float*)d_in[11];
    const float* out_w  = (const float*)d_in[12];
    const float* gnw    = (const float*)d_in[13];
    const float* gnb    = (const float*)d_in[14];

    char* wsb = (char*)d_ws;
    const size_t MB = 1 << 20;
    h16*   wb    = (h16*)  (wsb);             // 14 MB (7 x 2MB f16 weights)
    h16*   xs    = (h16*)  (wsb + 14 * MB);   //  8 MB
    h16*   a_r   = (h16*)  (wsb + 22 * MB);   //  8 MB each
    h16*   a_k   = (h16*)  (wsb + 30 * MB);
    h16*   a_v   = (h16*)  (wsb + 38 * MB);
    h16*   a_g   = (h16*)  (wsb + 46 * MB);
    h16*   a_w   = (h16*)  (wsb + 54 * MB);
    h16*   rb    = (h16*)  (wsb + 62 * MB);   //  8 MB each
    h16*   kb    = (h16*)  (wsb + 70 * MB);
    h16*   vb    = (h16*)  (wsb + 78 * MB);
    h16*   gb    = (h16*)  (wsb + 86 * MB);
    h16*   ewb   = (h16*)  (wsb + 94 * MB);
    h16*   gated = (h16*)  (wsb + 102 * MB);  //  8 MB (end: 110 MB)
    // overlays on the a_* region (dead once the 5 projections are done):
    h16*   Abuf  = (h16*)  (wsb + 22 * MB);   //  8.4 MB (f16, in-place A->S)
    float* Pbuf  = (float*)(wsb + 31 * MB);   //  0.25 MB

    // 1. weights -> f16 + x_shift -> f16 (fused)
    prep<<<7 * 512 + 2048, 256, 0, stream>>>(ddw, r_w, k_w, v_w, g_w, w_w, out_w,
                                             wb, x, xs);
    // 2. dd GEMM + fused 5-way lerp -> f16 activations (64x128 tile, 512 blk)
    dim3 gg64(8, 64);
    gemm_ddlerp<<<gg64, 256, 0, stream>>>(xs, wb, x, mix_r, mix_k, mix_v, mix_g, mix_w,
                                          a_r, a_k, a_v, a_g, a_w);
    // 3. batched projections (r,k,v,g-silu,w-exp) -> f16 (128^2 tile)
    dim3 gg5(8, 32, 5);
    gemm5<<<gg5, 256, 0, stream>>>(a_r, a_k, a_v, a_g, a_w, wb, rb, kb, vb, gb, ewb);
    // 4-6. chunked WKV scan; pass2 fuses GroupNorm + gate
    wkv_pass1<<<32 * NC, 256, 0, stream>>>(kb, vb, ewb, Abuf, Pbuf);
    wkv_combine<<<32 * 4, 256, 0, stream>>>(Abuf, Pbuf);
    wkv_pass2<<<32 * NC, 256, 0, stream>>>(rb, kb, vb, ewb, Abuf, gb, gnw, gnb, gated);
    // 7. output projection (f32 out, 64x128 tile, 512 blocks)
    gemm_bt_f<<<gg64, 256, 0, stream>>>(gated, wb + 6 * 1048576, (float*)d_out);
    (void)in_sizes; (void)n_in; (void)out_size; (void)ws_size;
}

// Round 22
// 184.919 us; speedup vs baseline: 1.0516x; 1.0387x over previous
//
#include <hip/hip_runtime.h>
#include <math.h>

typedef _Float16 h16;
typedef _Float16 h16x4 __attribute__((ext_vector_type(4)));
typedef _Float16 h16x8 __attribute__((ext_vector_type(8)));
typedef float    f32x4 __attribute__((ext_vector_type(4)));

#define Bsz 2
#define Tsz 2048
#define Dsz 1024
#define Hn  16
#define DH  64
#define NC  32         // scan chunks
#define NCSH 5
#define CL  (Tsz/NC)   // 64 steps per chunk
#define TS  16         // steps per LDS tile (scan)
#define NTL (CL/TS)    // 4 tiles per chunk
#define LP  68         // padded LDS row (floats) for scan tiles

// ---------------------------------------------------------------------------
// prep: fused weight-convert (blocks 0..3583) + x_shift build (3584..5631).
__global__ void prep(const float* __restrict__ s0, const float* __restrict__ s1,
                     const float* __restrict__ s2, const float* __restrict__ s3,
                     const float* __restrict__ s4, const float* __restrict__ s5,
                     const float* __restrict__ s6, h16* __restrict__ dst,
                     const float* __restrict__ x, h16* __restrict__ xs) {
    int blk = blockIdx.x;
    if (blk < 7 * 512) {
        int seg = blk >> 9;
        int li  = ((blk & 511) << 8) + threadIdx.x;
        const float* sp;
        switch (seg) {
            case 0: sp = s0; break; case 1: sp = s1; break; case 2: sp = s2; break;
            case 3: sp = s3; break; case 4: sp = s4; break; case 5: sp = s5; break;
            default: sp = s6; break;
        }
        size_t e = (size_t)li * 8;
        f32x4 a = *(const f32x4*)(sp + e);
        f32x4 b = *(const f32x4*)(sp + e + 4);
        h16x8 o;
        #pragma unroll
        for (int j = 0; j < 4; ++j) { o[j] = (h16)a[j]; o[j + 4] = (h16)b[j]; }
        *(h16x8*)(dst + (size_t)seg * 1048576 + e) = o;
    } else {
        int li = ((blk - 7 * 512) << 8) + threadIdx.x;
        size_t e = (size_t)li * 8;
        int tok = (int)(e >> 10);
        int t   = tok & (Tsz - 1);
        h16x8 o;
        if (t > 0) {
            f32x4 a = *(const f32x4*)(x + e - Dsz);
            f32x4 b = *(const f32x4*)(x + e - Dsz + 4);
            #pragma unroll
            for (int j = 0; j < 4; ++j) { o[j] = (h16)a[j]; o[j + 4] = (h16)b[j]; }
        } else {
            #pragma unroll
            for (int j = 0; j < 8; ++j) o[j] = (h16)0.f;
        }
        *(h16x8*)(xs + e) = o;
    }
}

// ---------------------------------------------------------------------------
#define BK 32

__device__ __forceinline__ void gld16(const void* g, void* l) {
    __builtin_amdgcn_global_load_lds(
        (const __attribute__((address_space(1))) void*)g,
        (__attribute__((address_space(3))) void*)l, 16, 0, 0);
}

// ============ gemm5: 128x128 tile, 512-thread (8-wave) blocks (r22) =========
// Mechanism: r17's 4-wave blocks at 2 blocks/CU gave only 8 waves/CU (2/SIMD)
// — wave-overlap starved. 8-wave blocks at same 80KB LDS -> 16 waves/CU
// (4/SIMD). Per wave: 64x32 subtile (acc 4x2); staging = 1 A + 1 B gld16 per
// thread (512 threads cover 128x32 per call). Depth-4 counted vmcnt:
// 2 loads/stage -> steady vmcnt(6), tail 4/2/0. Swizzle: source chunk
// (tid&3)^((tid>>3)&3) (row-dependent, same as r17's per-64-row form);
// read side unchanged (depends only on row mod 16).
__global__ __launch_bounds__(512) void gemm5(
        const h16* __restrict__ A0, const h16* __restrict__ A1,
        const h16* __restrict__ A2, const h16* __restrict__ A3,
        const h16* __restrict__ A4, const h16* __restrict__ Wb,
        h16* __restrict__ C0, h16* __restrict__ C1,
        h16* __restrict__ C2, h16* __restrict__ C3,
        h16* __restrict__ C4) {
    __shared__ h16 As[5][4096];   // 5 x 8KB (128x32)
    __shared__ h16 Bs[5][4096];
    int z = blockIdx.z;
    const h16* A; h16* C; int epi;
    switch (z) {
        case 0: A = A0; C = C0; epi = 0; break;
        case 1: A = A1; C = C1; epi = 0; break;
        case 2: A = A2; C = C2; epi = 0; break;
        case 3: A = A3; C = C3; epi = 2; break;
        default: A = A4; C = C4; epi = 3; break;
    }
    const h16* W = Wb + (size_t)(z + 1) * 1048576;

    const int tid  = threadIdx.x;
    const int lane = tid & 63;
    const int wave = tid >> 6;        // 0..7
    const int wm = (wave >> 2) * 64;  // 2 row halves
    const int wn = (wave & 3) * 32;   // 4 col strips
    const int lin = blockIdx.y * 8 + blockIdx.x;      // 0..255
    const int g8  = lin & 7, sq = lin >> 3;
    const int bm  = (g8 * 4 + (sq >> 3)) * 128;
    const int bn  = (sq & 7) * 128;
    const int K = 1024;

    f32x4 acc[4][2];
    #pragma unroll
    for (int a = 0; a < 4; ++a)
        #pragma unroll
        for (int b = 0; b < 2; ++b) acc[a][b] = (f32x4)(0.f);

    // staging: thread t covers row t>>2 (0..127), phys chunk t&3;
    // source chunk pre-swizzled (both-sides rule).
    const int srow = tid >> 2;
    const int scol = (((tid & 3) ^ ((tid >> 3) & 3)) << 3);
    const h16* gA0 = A + (size_t)(bm + srow) * K + scol;
    const h16* gB0 = W + (size_t)(bn + srow) * K + scol;

    const int pcq = (lane >> 4) ^ ((lane >> 1) & 3);
    const int fro = (lane & 15) * BK + pcq * 8;

    auto stage = [&](int b, int k0) {
        gld16(gA0 + k0, &As[b][tid * 8]);
        gld16(gB0 + k0, &Bs[b][tid * 8]);
    };
    auto compute = [&](int b) {
        const h16* as = As[b]; const h16* bs = Bs[b];
        h16x8 af[4], bfr[2];
        #pragma unroll
        for (int mi = 0; mi < 4; ++mi)
            af[mi] = *(const h16x8*)(as + (wm + mi * 16) * BK + fro);
        #pragma unroll
        for (int ni = 0; ni < 2; ++ni)
            bfr[ni] = *(const h16x8*)(bs + (wn + ni * 16) * BK + fro);
        __builtin_amdgcn_s_setprio(1);
        #pragma unroll
        for (int mi = 0; mi < 4; ++mi)
            #pragma unroll
            for (int ni = 0; ni < 2; ++ni)
                acc[mi][ni] = __builtin_amdgcn_mfma_f32_16x16x32_f16(
                    af[mi], bfr[ni], acc[mi][ni], 0, 0, 0);
        __builtin_amdgcn_s_setprio(0);
    };

    stage(0, 0);
    stage(1, BK);
    stage(2, 2 * BK);
    stage(3, 3 * BK);
    #pragma unroll
    for (int t = 0; t < 32; ++t) {
        if (t <= 28)      { asm volatile("s_waitcnt vmcnt(6)" ::: "memory"); }
        else if (t == 29) { asm volatile("s_waitcnt vmcnt(4)" ::: "memory"); }
        else if (t == 30) { asm volatile("s_waitcnt vmcnt(2)" ::: "memory"); }
        else              { asm volatile("s_waitcnt vmcnt(0)" ::: "memory"); }
        __builtin_amdgcn_sched_barrier(0);
        __builtin_amdgcn_s_barrier();
        __builtin_amdgcn_sched_barrier(0);
        if (t + 4 < 32) stage((t + 4) % 5, (t + 4) * BK);
        compute(t % 5);
    }

    const int colb = bn + wn + (lane & 15);
    const int rowb = bm + wm + (lane >> 4) * 4;
    #pragma unroll
    for (int mi = 0; mi < 4; ++mi)
        #pragma unroll
        for (int ni = 0; ni < 2; ++ni)
            #pragma unroll
            for (int j = 0; j < 4; ++j) {
                float y = acc[mi][ni][j];
                if (epi == 2)      { y = y / (1.f + __expf(-y)); }
                else if (epi == 3) { y = 0.60653065971263342f / (1.f + __expf(-y)); }
                C[(size_t)(rowb + mi * 16 + j) * 1024 + colb + ni * 16] = (h16)y;
            }
}

// ============ 64x128 kloop (r21: single-GEMM dispatches, 512 blocks) ========
struct GemmCtx64 {
    f32x4 acc[4][2];
    int bm, bn, lane, wave, wn;
};

__device__ __forceinline__ void gemm_kloop64(GemmCtx64& cx, const h16* __restrict__ A,
                                             const h16* __restrict__ W) {
    __shared__ h16 As[5][2048];   // 5 x 4KB (64x32)
    __shared__ h16 Bs[5][4096];   // 5 x 8KB (128x32)
    const int tid  = threadIdx.x;
    const int lane = tid & 63;
    const int wave = tid >> 6;
    cx.lane = lane; cx.wave = wave;
    cx.wn = wave * 32;
    const int lin = blockIdx.y * 8 + blockIdx.x;      // 0..511
    const int g8  = lin & 7, sq = lin >> 3;           // sq 0..63
    cx.bm = (g8 * 8 + (sq >> 3)) * 64;
    cx.bn = (sq & 7) * 128;
    const int K = 1024;

    #pragma unroll
    for (int a = 0; a < 4; ++a)
        #pragma unroll
        for (int b = 0; b < 2; ++b) cx.acc[a][b] = (f32x4)(0.f);

    const int srow = (wave << 4) + (lane >> 2);
    const int scol = (((lane & 3) ^ ((lane >> 3) & 3)) << 3);
    const h16* gA0 = A + (size_t)(cx.bm + srow) * K + scol;
    const h16* gB0 = W + (size_t)(cx.bn + srow) * K + scol;
    const h16* gB1 = gB0 + (size_t)64 * K;

    const int pcq = (lane >> 4) ^ ((lane >> 1) & 3);
    const int fro = (lane & 15) * BK + pcq * 8;

    auto stage = [&](int b, int k0) {
        gld16(gA0 + k0, &As[b][wave * 512]);
        gld16(gB0 + k0, &Bs[b][wave * 512]);
        gld16(gB1 + k0, &Bs[b][2048 + wave * 512]);
    };
    auto compute = [&](int b) {
        const h16* as = As[b]; const h16* bs = Bs[b];
        h16x8 af[4], bfr[2];
        #pragma unroll
        for (int mi = 0; mi < 4; ++mi)
            af[mi] = *(const h16x8*)(as + (mi * 16) * BK + fro);
        #pragma unroll
        for (int ni = 0; ni < 2; ++ni)
            bfr[ni] = *(const h16x8*)(bs + (cx.wn + ni * 16) * BK + fro);
        __builtin_amdgcn_s_setprio(1);
        #pragma unroll
        for (int mi = 0; mi < 4; ++mi)
            #pragma unroll
            for (int ni = 0; ni < 2; ++ni)
                cx.acc[mi][ni] = __builtin_amdgcn_mfma_f32_16x16x32_f16(
                    af[mi], bfr[ni], cx.acc[mi][ni], 0, 0, 0);
        __builtin_amdgcn_s_setprio(0);
    };

    stage(0, 0);
    stage(1, BK);
    stage(2, 2 * BK);
    stage(3, 3 * BK);
    #pragma unroll
    for (int t = 0; t < 32; ++t) {
        if (t <= 28)      { asm volatile("s_waitcnt vmcnt(9)" ::: "memory"); }
        else if (t == 29) { asm volatile("s_waitcnt vmcnt(6)" ::: "memory"); }
        else if (t == 30) { asm volatile("s_waitcnt vmcnt(3)" ::: "memory"); }
        else              { asm volatile("s_waitcnt vmcnt(0)" ::: "memory"); }
        __builtin_amdgcn_sched_barrier(0);
        __builtin_amdgcn_s_barrier();
        __builtin_amdgcn_sched_barrier(0);
        if (t + 4 < 32) stage((t + 4) % 5, (t + 4) * BK);
        compute(t % 5);
    }
}

__global__ __launch_bounds__(256) void gemm_bt_f(const h16* __restrict__ A,
                                                 const h16* __restrict__ W,
                                                 float* __restrict__ C) {
    GemmCtx64 cx;
    gemm_kloop64(cx, A, W);
    const int colb = cx.bn + cx.wn + (cx.lane & 15);
    const int rowb = cx.bm + (cx.lane >> 4) * 4;
    #pragma unroll
    for (int mi = 0; mi < 4; ++mi)
        #pragma unroll
        for (int ni = 0; ni < 2; ++ni)
            #pragma unroll
            for (int j = 0; j < 4; ++j)
                C[(size_t)(rowb + mi * 16 + j) * 1024 + colb + ni * 16] = cx.acc[mi][ni][j];
}

// dd GEMM with fused 5-way lerp epilogue (fast-exp tanh/sigmoid);
// x_shift read from A (== xs, h16).
__global__ __launch_bounds__(256) void gemm_ddlerp(const h16* __restrict__ A,
                                                   const h16* __restrict__ W,
                                                   const float* __restrict__ x,
                                                   const float* __restrict__ mr,
                                                   const float* __restrict__ mk,
                                                   const float* __restrict__ mv,
                                                   const float* __restrict__ mg,
                                                   const float* __restrict__ mw,
                                                   h16* __restrict__ ar, h16* __restrict__ ak,
                                                   h16* __restrict__ av, h16* __restrict__ ag,
                                                   h16* __restrict__ aw) {
    GemmCtx64 cx;
    gemm_kloop64(cx, A, W);
    const int colb = cx.bn + cx.wn + (cx.lane & 15);
    const int rowb = cx.bm + (cx.lane >> 4) * 4;
    #pragma unroll
    for (int mi = 0; mi < 4; ++mi)
        #pragma unroll
        for (int j = 0; j < 4; ++j) {
            int m = rowb + mi * 16 + j;
            #pragma unroll
            for (int ni = 0; ni < 2; ++ni) {
                int d = colb + ni * 16;
                size_t e = (size_t)m * 1024 + d;
                float y  = cx.acc[mi][ni][j];
                float th = 1.f - 2.f / (__expf(2.f * y) + 1.f);
                float dv = 1.f / (1.f + __expf(-th));
                float xv  = x[e];
                float xsv = (float)A[e];
                float dxx = xv - xsv;
                float m0 = mr[d], m1 = mk[d], m2 = mv[d], m3 = mg[d], m4 = mw[d];
                ar[e] = (h16)(xsv + dxx * (m0 + dv * (1.f - m0)));
                ak[e] = (h16)(xsv + dxx * (m1 + dv * (1.f - m1)));
                av[e] = (h16)(xsv + dxx * (m2 + dv * (1.f - m2)));
                ag[e] = (h16)(xsv + dxx * (m3 + dv * (1.f - m3)));
                aw[e] = (h16)(xsv + dxx * (m4 + dv * (1.f - m4)));
            }
        }
}

// ---------------------------------------------------------------------------
// WKV scan, NC=32; f16 globals + f16 state. (r20 known-good)
__device__ __forceinline__ void cvt16(const h16x8 u0, const h16x8 u1,
                                      f32x4& t0, f32x4& t1, f32x4& t2, f32x4& t3) {
    #pragma unroll
    for (int j = 0; j < 4; ++j) {
        t0[j] = (float)u0[j];     t1[j] = (float)u0[j + 4];
        t2[j] = (float)u1[j];     t3[j] = (float)u1[j + 4];
    }
}

__global__ __launch_bounds__(256) void wkv_pass1(const h16* __restrict__ kk,
                                                 const h16* __restrict__ vv,
                                                 const h16* __restrict__ ew,
                                                 h16* __restrict__ Abuf,
                                                 float* __restrict__ Pbuf) {
    __shared__ float lds[2][3][TS][LP];
    int blk = blockIdx.x;
    int bh = blk >> NCSH, c = blk & (NC - 1);
    int b = bh >> 4, h = bh & 15;
    int tid = threadIdx.x;
    int i = tid >> 2, q = tid & 3, j0 = q * 16;
    int w = tid >> 6, idx = tid & 63;
    int ss = idx >> 2, qq = idx & 3;
    const h16* sarr = (w == 0) ? ew : (w == 1) ? kk : vv;

    float st[16];
    #pragma unroll
    for (int jj = 0; jj < 16; ++jj) st[jj] = 0.f;
    float pp = 1.f;

    size_t cbase = ((size_t)b * Tsz + (size_t)c * CL) * Dsz + h * DH;

    if (w < 3) {
        const h16x8* g = (const h16x8*)(sarr + cbase + (size_t)ss * Dsz + qq * 16);
        h16x8 u0 = g[0], u1 = g[1];
        f32x4 t0, t1, t2, t3;
        cvt16(u0, u1, t0, t1, t2, t3);
        f32x4* d = (f32x4*)&lds[0][w][ss][qq * 16];
        d[0] = t0; d[1] = t1; d[2] = t2; d[3] = t3;
    }
    __syncthreads();

    for (int tl = 0; tl < NTL; ++tl) {
        int cur = tl & 1;
        h16x8 u0, u1;
        bool pf = (tl + 1 < NTL) && (w < 3);
        if (pf) {
            const h16x8* g = (const h16x8*)(sarr + cbase + (size_t)(tl + 1) * TS * Dsz
                                            + (size_t)ss * Dsz + qq * 16);
            u0 = g[0]; u1 = g[1];
        }
        #pragma unroll 4
        for (int s = 0; s < TS; ++s) {
            float ewi = lds[cur][0][s][i];
            float ki  = lds[cur][1][s][i];
            const float* vrow = &lds[cur][2][s][0];
            f32x4 v0 = *(const f32x4*)(vrow + j0);
            f32x4 v1 = *(const f32x4*)(vrow + j0 + 4);
            f32x4 v2 = *(const f32x4*)(vrow + j0 + 8);
            f32x4 v3 = *(const f32x4*)(vrow + j0 + 12);
            #pragma unroll
            for (int jj = 0; jj < 4; ++jj) {
                st[jj]      = fmaf(st[jj],      ewi, ki * v0[jj]);
                st[jj + 4]  = fmaf(st[jj + 4],  ewi, ki * v1[jj]);
                st[jj + 8]  = fmaf(st[jj + 8],  ewi, ki * v2[jj]);
                st[jj + 12] = fmaf(st[jj + 12], ewi, ki * v3[jj]);
            }
            pp *= ewi;
        }
        if (pf) {
            f32x4 t0, t1, t2, t3;
            cvt16(u0, u1, t0, t1, t2, t3);
            f32x4* d = (f32x4*)&lds[cur ^ 1][w][ss][qq * 16];
            d[0] = t0; d[1] = t1; d[2] = t2; d[3] = t3;
        }
        __syncthreads();
    }

    size_t ob = (size_t)blk * 4096 + (size_t)i * 64 + j0;
    h16x8 s0, s1;
    #pragma unroll
    for (int jj = 0; jj < 8; ++jj) { s0[jj] = (h16)st[jj]; s1[jj] = (h16)st[jj + 8]; }
    *(h16x8*)(Abuf + ob)     = s0;
    *(h16x8*)(Abuf + ob + 8) = s1;
    if (q == 0) Pbuf[blk * 64 + i] = pp;
}

// IN-PLACE combine, j-split x4 (grid 128 blocks), depth-2 prefetch, f16 state.
__global__ __launch_bounds__(256) void wkv_combine(h16* __restrict__ AS,
                                                   const float* __restrict__ Pbuf) {
    int bh = blockIdx.x >> 2, jq = blockIdx.x & 3;
    int tid = threadIdx.x;
    int i = tid >> 2, sc = tid & 3;
    int off = i * 64 + jq * 16 + sc * 4;
    float s[4] = {0.f, 0.f, 0.f, 0.f};
    size_t base = (size_t)(bh * NC) * 4096 + off;
    h16x4 a0 = *(const h16x4*)(AS + base);
    float p0 = Pbuf[bh * NC * 64 + i];
    h16x4 a1 = *(const h16x4*)(AS + base + 4096);
    float p1 = Pbuf[(bh * NC + 1) * 64 + i];
    for (int c = 0; c < NC; ++c) {
        h16x4 a2{}; float p2 = 0.f;
        if (c + 2 < NC) {
            a2 = *(const h16x4*)(AS + base + 2 * 4096);
            p2 = Pbuf[(bh * NC + c + 2) * 64 + i];
        }
        h16x4 so;
        #pragma unroll
        for (int j = 0; j < 4; ++j) so[j] = (h16)s[j];
        *(h16x4*)(AS + base) = so;
        #pragma unroll
        for (int j = 0; j < 4; ++j) s[j] = fmaf(s[j], p0, (float)a0[j]);
        a0 = a1; p0 = p1; a1 = a2; p1 = p2;
        base += 4096;
    }
}

// pass2 + fused GroupNorm/gate (r20 known-good).
__global__ __launch_bounds__(256) void wkv_pass2(const h16* __restrict__ rr,
                                                 const h16* __restrict__ kk,
                                                 const h16* __restrict__ vv,
                                                 const h16* __restrict__ ew,
                                                 const h16* __restrict__ Sbuf,
                                                 const h16* __restrict__ gb,
                                                 const float* __restrict__ gnw,
                                                 const float* __restrict__ gnb,
                                                 h16* __restrict__ gated) {
    __shared__ float lds[2][4][TS][LP];
    __shared__ float po_buf[TS][65];
    int blk = blockIdx.x;
    int bh = blk >> NCSH, c = blk & (NC - 1);
    int b = bh >> 4, h = bh & 15;
    int tid = threadIdx.x;
    int i = tid >> 2, q = tid & 3, j0 = q * 16;
    int w = tid >> 6, idx = tid & 63;
    int ss = idx >> 2, qq = idx & 3;
    const h16* sarr = (w == 0) ? ew : (w == 1) ? kk : (w == 2) ? vv : rr;

    const int lane = tid & 63;
    const float gw = gnw[h * 64 + lane];
    const float gbv = gnb[h * 64 + lane];

    float st[16];
    {
        size_t ob = (size_t)blk * 4096 + (size_t)i * 64 + j0;
        h16x8 s0 = *(const h16x8*)(Sbuf + ob);
        h16x8 s1 = *(const h16x8*)(Sbuf + ob + 8);
        #pragma unroll
        for (int jj = 0; jj < 8; ++jj) { st[jj] = (float)s0[jj]; st[jj + 8] = (float)s1[jj]; }
    }

    size_t cbase = ((size_t)b * Tsz + (size_t)c * CL) * Dsz + h * DH;

    {
        const h16x8* g = (const h16x8*)(sarr + cbase + (size_t)ss * Dsz + qq * 16);
        h16x8 u0 = g[0], u1 = g[1];
        f32x4 t0, t1, t2, t3;
        cvt16(u0, u1, t0, t1, t2, t3);
        f32x4* d = (f32x4*)&lds[0][w][ss][qq * 16];
        d[0] = t0; d[1] = t1; d[2] = t2; d[3] = t3;
    }
    __syncthreads();

    for (int tl = 0; tl < NTL; ++tl) {
        int cur = tl & 1;
        h16x8 u0, u1;
        bool pf = (tl + 1 < NTL);
        if (pf) {
            const h16x8* g = (const h16x8*)(sarr + cbase + (size_t)(tl + 1) * TS * Dsz
                                            + (size_t)ss * Dsz + qq * 16);
            u0 = g[0]; u1 = g[1];
        }
        size_t gt = cbase + (size_t)tl * TS * Dsz;
        #pragma unroll 4
        for (int s = 0; s < TS; ++s) {
            float ewi = lds[cur][0][s][i];
            float ki  = lds[cur][1][s][i];
            const float* vrow = &lds[cur][2][s][0];
            const float* rrow = &lds[cur][3][s][0];
            f32x4 v0 = *(const f32x4*)(vrow + j0);
            f32x4 v1 = *(const f32x4*)(vrow + j0 + 4);
            f32x4 v2 = *(const f32x4*)(vrow + j0 + 8);
            f32x4 v3 = *(const f32x4*)(vrow + j0 + 12);
            f32x4 r0 = *(const f32x4*)(rrow + j0);
            f32x4 r1 = *(const f32x4*)(rrow + j0 + 4);
            f32x4 r2 = *(const f32x4*)(rrow + j0 + 8);
            f32x4 r3 = *(const f32x4*)(rrow + j0 + 12);
            float po = 0.f;
            #pragma unroll
            for (int jj = 0; jj < 4; ++jj) {
                st[jj]      = fmaf(st[jj],      ewi, ki * v0[jj]);
                st[jj + 4]  = fmaf(st[jj + 4],  ewi, ki * v1[jj]);
                st[jj + 8]  = fmaf(st[jj + 8],  ewi, ki * v2[jj]);
                st[jj + 12] = fmaf(st[jj + 12], ewi, ki * v3[jj]);
                po = fmaf(st[jj],      r0[jj], po);
                po = fmaf(st[jj + 4],  r1[jj], po);
                po = fmaf(st[jj + 8],  r2[jj], po);
                po = fmaf(st[jj + 12], r3[jj], po);
            }
            po += __shfl_xor(po, 1, 64);
            po += __shfl_xor(po, 2, 64);
            if (q == 0) po_buf[s][i] = po;
        }
        __syncthreads();
        #pragma unroll
        for (int k2 = 0; k2 < 4; ++k2) {
            int s2 = w * 4 + k2;
            float val = po_buf[s2][lane];
            float sm = val, sm2 = val * val;
            #pragma unroll
            for (int m = 1; m < 64; m <<= 1) {
                sm  += __shfl_xor(sm, m, 64);
                sm2 += __shfl_xor(sm2, m, 64);
            }
            float mean = sm * (1.f / 64.f);
            float var  = sm2 * (1.f / 64.f) - mean * mean;
            float y = (val - mean) * rsqrtf(var + 0.00064f);
            y = y * gw + gbv;
            size_t ge = gt + (size_t)s2 * Dsz + lane;
            y *= (float)gb[ge];
            gated[ge] = (h16)y;
        }
        if (pf) {
            f32x4 t0, t1, t2, t3;
            cvt16(u0, u1, t0, t1, t2, t3);
            f32x4* d = (f32x4*)&lds[cur ^ 1][w][ss][qq * 16];
            d[0] = t0; d[1] = t1; d[2] = t2; d[3] = t3;
        }
        __syncthreads();
    }
}

// ---------------------------------------------------------------------------
extern "C" void kernel_launch(void* const* d_in, const int* in_sizes, int n_in,
                              void* d_out, int out_size, void* d_ws, size_t ws_size,
                              hipStream_t stream) {
    const float* x      = (const float*)d_in[0];
    const float* ddw    = (const float*)d_in[1];
    const float* mix_r  = (const float*)d_in[2];
    const float* mix_k  = (const float*)d_in[3];
    const float* mix_v  = (const float*)d_in[4];
    const float* mix_g  = (const float*)d_in[5];
    const float* mix_w  = (const float*)d_in[6];
    const float* r_w    = (const float*)d_in[7];
    const float* k_w    = (const float*)d_in[8];
    const float* v_w    = (const float*)d_in[9];
    const float* g_w    = (const float*)d_in[10];
    const float* w_w    = (const float*)d_in[11];
    const float* out_w  = (const float*)d_in[12];
    const float* gnw    = (const float*)d_in[13];
    const float* gnb    = (const float*)d_in[14];

    char* wsb = (char*)d_ws;
    const size_t MB = 1 << 20;
    h16*   wb    = (h16*)  (wsb);             // 14 MB (7 x 2MB f16 weights)
    h16*   xs    = (h16*)  (wsb + 14 * MB);   //  8 MB
    h16*   a_r   = (h16*)  (wsb + 22 * MB);   //  8 MB each
    h16*   a_k   = (h16*)  (wsb + 30 * MB);
    h16*   a_v   = (h16*)  (wsb + 38 * MB);
    h16*   a_g   = (h16*)  (wsb + 46 * MB);
    h16*   a_w   = (h16*)  (wsb + 54 * MB);
    h16*   rb    = (h16*)  (wsb + 62 * MB);   //  8 MB each
    h16*   kb    = (h16*)  (wsb + 70 * MB);
    h16*   vb    = (h16*)  (wsb + 78 * MB);
    h16*   gb    = (h16*)  (wsb + 86 * MB);
    h16*   ewb   = (h16*)  (wsb + 94 * MB);
    h16*   gated = (h16*)  (wsb + 102 * MB);  //  8 MB (end: 110 MB)
    // overlays on the a_* region (dead once the 5 projections are done):
    h16*   Abuf  = (h16*)  (wsb + 22 * MB);   //  8.4 MB (f16, in-place A->S)
    float* Pbuf  = (float*)(wsb + 31 * MB);   //  0.25 MB

    // 1. weights -> f16 + x_shift -> f16 (fused)
    prep<<<7 * 512 + 2048, 256, 0, stream>>>(ddw, r_w, k_w, v_w, g_w, w_w, out_w,
                                             wb, x, xs);
    // 2. dd GEMM + fused 5-way lerp -> f16 activations (64x128 tile, 512 blk)
    dim3 gg64(8, 64);
    gemm_ddlerp<<<gg64, 256, 0, stream>>>(xs, wb, x, mix_r, mix_k, mix_v, mix_g, mix_w,
                                          a_r, a_k, a_v, a_g, a_w);
    // 3. batched projections (r,k,v,g-silu,w-exp) -> f16 (128^2, 8-wave blocks)
    dim3 gg5(8, 32, 5);
    gemm5<<<gg5, 512, 0, stream>>>(a_r, a_k, a_v, a_g, a_w, wb, rb, kb, vb, gb, ewb);
    // 4-6. chunked WKV scan; pass2 fuses GroupNorm + gate
    wkv_pass1<<<32 * NC, 256, 0, stream>>>(kb, vb, ewb, Abuf, Pbuf);
    wkv_combine<<<32 * 4, 256, 0, stream>>>(Abuf, Pbuf);
    wkv_pass2<<<32 * NC, 256, 0, stream>>>(rb, kb, vb, ewb, Abuf, gb, gnw, gnb, gated);
    // 7. output projection (f32 out, 64x128 tile, 512 blocks)
    gemm_bt_f<<<gg64, 256, 0, stream>>>(gated, wb + 6 * 1048576, (float*)d_out);
    (void)in_sizes; (void)n_in; (void)out_size; (void)ws_size;
}